// Round 6
// baseline (352.543 us; speedup 1.0000x reference)
//
#include <hip/hip_runtime.h>
#include <stdint.h>

// Problem constants: B=2, N=2048, A=256, H=8, KD=VD=32
#define NTOK 2048
#define SCALE 0.17677669529663687f  // 1/sqrt(32)

typedef short s16x8 __attribute__((ext_vector_type(8)));      // MFMA A/B frag (8 bf16)
typedef unsigned short u16x8 __attribute__((ext_vector_type(8)));
typedef float f32x4 __attribute__((ext_vector_type(4)));      // MFMA C/D frag

__device__ __forceinline__ unsigned short f2bf(float f) {
  unsigned int u = __builtin_bit_cast(unsigned int, f);
  u += 0x7fffu + ((u >> 16) & 1u);  // RNE
  return (unsigned short)(u >> 16);
}

// ---------------- Kernel 1: weight transpose + bf16 convert ----------------
__global__ __launch_bounds__(256) void prep_weights_k(
    const float* __restrict__ qw, const float* __restrict__ kw,
    const float* __restrict__ vw, const float* __restrict__ gw,
    unsigned short* __restrict__ Wt) {
  __shared__ float tile[64][68];
  const int p = blockIdx.z;
  const int a0 = blockIdx.x * 64;
  const int n0 = blockIdx.y * 64;
  const float* src = (p == 0) ? qw : (p == 1) ? kw : (p == 2) ? vw : gw;
  const int tx = threadIdx.x & 15;
  const int ty = threadIdx.x >> 4;
#pragma unroll
  for (int kk = 0; kk < 4; kk++) {
    int ar = ty + kk * 16;
    float4 v = *reinterpret_cast<const float4*>(src + (a0 + ar) * 256 + n0 + tx * 4);
    tile[ar][tx * 4 + 0] = v.x; tile[ar][tx * 4 + 1] = v.y;
    tile[ar][tx * 4 + 2] = v.z; tile[ar][tx * 4 + 3] = v.w;
  }
  __syncthreads();
  unsigned short* dst = Wt + p * 65536;
#pragma unroll
  for (int kk = 0; kk < 4; kk++) {
    int nr = ty + kk * 16;
    ushort4 o;
    o.x = f2bf(tile[tx * 4 + 0][nr]);
    o.y = f2bf(tile[tx * 4 + 1][nr]);
    o.z = f2bf(tile[tx * 4 + 2][nr]);
    o.w = f2bf(tile[tx * 4 + 3][nr]);
    *reinterpret_cast<ushort4*>(dst + (n0 + nr) * 256 + a0 + tx * 4) = o;
  }
}

// ---------------- Kernel 2: fused QKVG projection GEMM (bf16 MFMA) ----------
__global__ __launch_bounds__(256) void proj_k(
    const float* __restrict__ x, const unsigned short* __restrict__ Wt,
    const float* __restrict__ query_b,
    unsigned short* __restrict__ Qg, unsigned short* __restrict__ Kg,
    unsigned short* __restrict__ Vt, float* __restrict__ gate) {
  const int w = threadIdx.x >> 6;
  const int lane = threadIdx.x & 63;
  const int l15 = lane & 15;
  const int quad = lane >> 4;
  const int p = blockIdx.y >> 1;
  const int half = blockIdx.y & 1;
  const int rbase = blockIdx.x * 128 + w * 32;
  const unsigned short* wp = Wt + p * 65536;

  f32x4 acc[2][8];
#pragma unroll
  for (int rt = 0; rt < 2; rt++)
#pragma unroll
    for (int ct = 0; ct < 8; ct++) acc[rt][ct] = (f32x4){0.f, 0.f, 0.f, 0.f};

  for (int ks = 0; ks < 8; ks++) {
    const int kb = ks * 32;
    s16x8 af[2];
#pragma unroll
    for (int rt = 0; rt < 2; rt++) {
      const float* xr = x + (rbase + rt * 16 + l15) * 256 + kb + quad * 8;
      float4 f0 = *reinterpret_cast<const float4*>(xr);
      float4 f1 = *reinterpret_cast<const float4*>(xr + 4);
      u16x8 t;
      t[0] = f2bf(f0.x); t[1] = f2bf(f0.y); t[2] = f2bf(f0.z); t[3] = f2bf(f0.w);
      t[4] = f2bf(f1.x); t[5] = f2bf(f1.y); t[6] = f2bf(f1.z); t[7] = f2bf(f1.w);
      af[rt] = __builtin_bit_cast(s16x8, t);
    }
#pragma unroll
    for (int ct = 0; ct < 8; ct++) {
      uint4 bv = *reinterpret_cast<const uint4*>(
          wp + (half * 128 + ct * 16 + l15) * 256 + kb + quad * 8);
      s16x8 bfr = __builtin_bit_cast(s16x8, bv);
#pragma unroll
      for (int rt = 0; rt < 2; rt++)
        acc[rt][ct] = __builtin_amdgcn_mfma_f32_16x16x32_bf16(af[rt], bfr, acc[rt][ct], 0, 0, 0);
    }
  }

#pragma unroll
  for (int ct = 0; ct < 8; ct++) {
    const int cgl = half * 128 + ct * 16 + l15;
    const int h = cgl >> 5, c = cgl & 31;
#pragma unroll
    for (int rt = 0; rt < 2; rt++) {
      const int n0r = rbase + rt * 16 + quad * 4;
      const int bidx = n0r >> 11;
      const int nl0 = n0r & 2047;
      if (p == 0) {
        const float qb = query_b[cgl];
#pragma unroll
        for (int i = 0; i < 4; i++) {
          float v = (acc[rt][ct][i] + qb) * SCALE;
          Qg[(size_t)((bidx * 8 + h) * 2048 + nl0 + i) * 32 + c] = f2bf(v);
        }
      } else if (p == 1) {
#pragma unroll
        for (int i = 0; i < 4; i++)
          Kg[(size_t)((bidx * 8 + h) * 2048 + nl0 + i) * 32 + c] = f2bf(acc[rt][ct][i]);
      } else if (p == 2) {
        ushort4 o;
        o.x = f2bf(acc[rt][ct][0]); o.y = f2bf(acc[rt][ct][1]);
        o.z = f2bf(acc[rt][ct][2]); o.w = f2bf(acc[rt][ct][3]);
        *reinterpret_cast<ushort4*>(Vt + (size_t)((bidx * 8 + h) * 32 + c) * 2048 + nl0) = o;
      } else {
#pragma unroll
        for (int i = 0; i < 4; i++) {
          float s = 1.f / (1.f + __expf(-acc[rt][ct][i]));
          gate[(size_t)(bidx * 2048 + nl0 + i) * 256 + cgl] = s;
        }
      }
    }
  }
}

// ---------------- Kernel 3: split-K batch-fused flash attention -------------
// v6 = v5 with __launch_bounds__(128, 2). History of the 2nd arg on this
// kernel: (128,1) -> VGPR 168 but residency pinned ~1 wave/SIMD (occupancy
// 10.4% even with 16 waves/CU in the grid; R5); (128,3) -> VGPR 84 + scratch
// spill (R4, 2.6x slower). (128,2) gives a 256-VGPR budget (no spill risk at
// ~168) and a 2-wave/SIMD residency target -> ~8 waves/CU from the 4x grid.
#define PST 136
__global__ __launch_bounds__(128, 2) void attn_k(
    const unsigned short* __restrict__ Qg, const unsigned short* __restrict__ Kg,
    const unsigned short* __restrict__ Vt, const float* __restrict__ bias,
    const float* __restrict__ nb, float* __restrict__ out,
    float* __restrict__ psum_g) {
  __shared__ unsigned short Ps[2 * 16 * PST];
  const int w = threadIdx.x >> 6;
  const int lane = threadIdx.x & 63;
  const int l15 = lane & 15;
  const int quad = lane >> 4;
  const int h = blockIdx.y;
  const int seg = blockIdx.z;           // 4-way key split: 512 keys each
  const int qbase = blockIdx.x * 32 + w * 16;
  const int qr0 = qbase + quad * 4;     // C-layout row of i=0
  const float* nbp = nb + (size_t)h * 2048 * 2048;
  unsigned short* Pw = Ps + w * 16 * PST;

  // Q A-frags for both batches.
  s16x8 aq[2];
#pragma unroll
  for (int bt = 0; bt < 2; bt++)
    aq[bt] = __builtin_bit_cast(s16x8, *reinterpret_cast<const uint4*>(
        Qg + (size_t)((bt * 8 + h) * 2048 + qbase + l15) * 32 + quad * 8));

  float psum[2][4];
  f32x4 o[2][2];
#pragma unroll
  for (int bt = 0; bt < 2; bt++)
#pragma unroll
    for (int i = 0; i < 4; i++) psum[bt][i] = 0.f;
#pragma unroll
  for (int bt = 0; bt < 2; bt++)
#pragma unroll
    for (int vt = 0; vt < 2; vt++) o[bt][vt] = (f32x4){0.f, 0.f, 0.f, 0.f};

  // Double-buffered register prefetch of this wave's nb slice (16q x 512k).
  const int kb0 = seg * 512;
  float nbuf[2][32];
#pragma unroll
  for (int ct = 0; ct < 8; ct++)
#pragma unroll
    for (int i = 0; i < 4; i++)
      nbuf[0][ct * 4 + i] = nbp[(size_t)(qr0 + i) * 2048 + kb0 + ct * 16 + l15];

#pragma unroll 2
  for (int t = 0; t < 4; t++) {
    const int kb = kb0 + t * 128;
    const int cur = t & 1, nxt = cur ^ 1;

#pragma unroll
    for (int bt = 0; bt < 2; bt++) {
      const unsigned short* Kp = Kg + (size_t)(bt * 8 + h) * 2048 * 32;
      const unsigned short* Vp = Vt + (size_t)(bt * 8 + h) * 32 * 2048;

      // K B-frags (contiguous 16B rows; L2-hot: 64 q-blocks share each slice).
      s16x8 bk[8];
#pragma unroll
      for (int ct = 0; ct < 8; ct++)
        bk[ct] = __builtin_bit_cast(s16x8, *reinterpret_cast<const uint4*>(
            Kp + (size_t)(kb + ct * 16 + l15) * 32 + quad * 8));
      // V B-frags (V^T rows, contiguous 16B).
      s16x8 vv[8];
#pragma unroll
      for (int kc = 0; kc < 4; kc++)
#pragma unroll
        for (int vt = 0; vt < 2; vt++)
          vv[kc * 2 + vt] = __builtin_bit_cast(s16x8, *reinterpret_cast<const uint4*>(
              Vp + (size_t)(vt * 16 + l15) * 2048 + kb + kc * 32 + quad * 8));
      // Key bias with static softmax max folded in.
      float bbv[8];
#pragma unroll
      for (int ct = 0; ct < 8; ct++)
        bbv[ct] = bias[bt * 2048 + kb + ct * 16 + l15] - 20.f;

      // Prefetch next tile's nb after this section's K/V loads.
      if (bt == 1 && t < 3) {
        const int kb2 = kb + 128;
#pragma unroll
        for (int ct = 0; ct < 8; ct++)
#pragma unroll
          for (int i = 0; i < 4; i++)
            nbuf[nxt][ct * 4 + i] = nbp[(size_t)(qr0 + i) * 2048 + kb2 + ct * 16 + l15];
      }

      // S = Q K^T (one MFMA per 16x16 tile: K=32 = full head dim).
      f32x4 s[8];
#pragma unroll
      for (int ct = 0; ct < 8; ct++)
        s[ct] = __builtin_amdgcn_mfma_f32_16x16x32_bf16(
            aq[bt], bk[ct], (f32x4){0.f, 0.f, 0.f, 0.f}, 0, 0, 0);

      // Static-max softmax: p = exp(s + bias + nb - 20); sum deferred.
#pragma unroll
      for (int ct = 0; ct < 8; ct++)
#pragma unroll
        for (int i = 0; i < 4; i++) {
          float pv = __expf(s[ct][i] + bbv[ct] + nbuf[cur][ct * 4 + i]);
          Pw[(quad * 4 + i) * PST + ct * 16 + l15] = f2bf(pv);
          psum[bt][i] += pv;
        }

      // PV: A = P from LDS (wave-private slice), B = V^T frags.
#pragma unroll
      for (int kc = 0; kc < 4; kc++) {
        s16x8 ap = __builtin_bit_cast(s16x8, *reinterpret_cast<const uint4*>(
            &Pw[l15 * PST + kc * 32 + quad * 8]));
#pragma unroll
        for (int vt = 0; vt < 2; vt++)
          o[bt][vt] = __builtin_amdgcn_mfma_f32_16x16x32_bf16(ap, vv[kc * 2 + vt],
                                                              o[bt][vt], 0, 0, 0);
      }
    }
  }

  // Epilogue: atomically accumulate split-K partials (unnormalized).
#pragma unroll
  for (int bt = 0; bt < 2; bt++)
#pragma unroll
    for (int i = 0; i < 4; i++) {
      float l = psum[bt][i];
      l += __shfl_xor(l, 1);
      l += __shfl_xor(l, 2);
      l += __shfl_xor(l, 4);
      l += __shfl_xor(l, 8);
      const int q = qr0 + i;
      if (l15 == 0) atomicAdd(&psum_g[(size_t)(bt * 8 + h) * 2048 + q], l);
#pragma unroll
      for (int vt = 0; vt < 2; vt++) {
        const int v = vt * 16 + l15;
        atomicAdd(&out[(size_t)(bt * 2048 + q) * 256 + h * 32 + v], o[bt][vt][i]);
      }
    }
}

// ---------------- Kernel 4: normalize + gate --------------------------------
__global__ __launch_bounds__(256) void finish_k(
    float* __restrict__ out, const float* __restrict__ gate,
    const float* __restrict__ psum_g) {
  const int i4 = blockIdx.x * 256 + threadIdx.x;   // float4 index, 262144 total
  const int flat = i4 * 4;
  const int b = flat >> 19;
  const int rem = flat & 524287;
  const int q = rem >> 8;
  const int c = rem & 255;
  const int h = c >> 5;
  const float inv = 1.f / psum_g[(size_t)(b * 8 + h) * 2048 + q];
  float4 o = reinterpret_cast<float4*>(out)[i4];
  float4 g = reinterpret_cast<const float4*>(gate)[i4];
  o.x *= inv * g.x; o.y *= inv * g.y; o.z *= inv * g.z; o.w *= inv * g.w;
  reinterpret_cast<float4*>(out)[i4] = o;
}

// ---------------- launch ----------------------------------------------------
extern "C" void kernel_launch(void* const* d_in, const int* in_sizes, int n_in,
                              void* d_out, int out_size, void* d_ws, size_t ws_size,
                              hipStream_t stream) {
  const float* q_data = (const float*)d_in[0];
  const float* bias = (const float*)d_in[1];
  const float* nbb = (const float*)d_in[2];
  const float* qw = (const float*)d_in[3];
  const float* qb = (const float*)d_in[4];
  const float* kw = (const float*)d_in[5];
  const float* vw = (const float*)d_in[6];
  const float* gw = (const float*)d_in[7];
  float* out = (float*)d_out;

  char* ws = (char*)d_ws;
  // ws layout (10.63 MB): Wt 512K | Qg 2M | Kg 2M | Vt 2M | gate 4M | psum 128K
  unsigned short* Wt = (unsigned short*)(ws + 0);
  unsigned short* Qg = (unsigned short*)(ws + 524288);
  unsigned short* Kg = (unsigned short*)(ws + 2621440);
  unsigned short* Vt = (unsigned short*)(ws + 4718592);
  float* gate = (float*)(ws + 6815744);
  float* psum_g = (float*)(ws + 11010048);

  hipMemsetAsync(out, 0, (size_t)out_size * sizeof(float), stream);
  hipMemsetAsync(psum_g, 0, 2 * 8 * 2048 * sizeof(float), stream);
  prep_weights_k<<<dim3(4, 4, 4), 256, 0, stream>>>(qw, kw, vw, gw, Wt);
  proj_k<<<dim3(32, 8), 256, 0, stream>>>(q_data, Wt, qb, Qg, Kg, Vt, gate);
  attn_k<<<dim3(64, 8, 4), 128, 0, stream>>>(Qg, Kg, Vt, bias, nbb, out, psum_g);
  finish_k<<<dim3(1024), 256, 0, stream>>>(out, gate, psum_g);
}

// Round 7
// 279.700 us; speedup vs baseline: 1.2604x; 1.2604x over previous
//
#include <hip/hip_runtime.h>
#include <stdint.h>

// Problem constants: B=2, N=2048, A=256, H=8, KD=VD=32
#define SCALE 0.17677669529663687f  // 1/sqrt(32)

typedef short s16x8 __attribute__((ext_vector_type(8)));      // MFMA A/B frag (8 bf16)
typedef unsigned short u16x8 __attribute__((ext_vector_type(8)));
typedef float f32x4 __attribute__((ext_vector_type(4)));      // MFMA C/D frag

__device__ __forceinline__ unsigned short f2bf(float f) {
  unsigned int u = __builtin_bit_cast(unsigned int, f);
  u += 0x7fffu + ((u >> 16) & 1u);  // RNE
  return (unsigned short)(u >> 16);
}

// Async global->LDS copy, 16B per lane (wave-uniform LDS base + lane*16).
__device__ __forceinline__ void gld_lds16(const float* g, float* l) {
  __builtin_amdgcn_global_load_lds(
      (const __attribute__((address_space(1))) void*)g,
      (__attribute__((address_space(3))) void*)l, 16, 0, 0);
}

// ---------------- Kernel 1: weight transpose + bf16 convert ----------------
__global__ __launch_bounds__(256) void prep_weights_k(
    const float* __restrict__ qw, const float* __restrict__ kw,
    const float* __restrict__ vw, const float* __restrict__ gw,
    unsigned short* __restrict__ Wt) {
  __shared__ float tile[64][68];
  const int p = blockIdx.z;
  const int a0 = blockIdx.x * 64;
  const int n0 = blockIdx.y * 64;
  const float* src = (p == 0) ? qw : (p == 1) ? kw : (p == 2) ? vw : gw;
  const int tx = threadIdx.x & 15;
  const int ty = threadIdx.x >> 4;
#pragma unroll
  for (int kk = 0; kk < 4; kk++) {
    int ar = ty + kk * 16;
    float4 v = *reinterpret_cast<const float4*>(src + (a0 + ar) * 256 + n0 + tx * 4);
    tile[ar][tx * 4 + 0] = v.x; tile[ar][tx * 4 + 1] = v.y;
    tile[ar][tx * 4 + 2] = v.z; tile[ar][tx * 4 + 3] = v.w;
  }
  __syncthreads();
  unsigned short* dst = Wt + p * 65536;
#pragma unroll
  for (int kk = 0; kk < 4; kk++) {
    int nr = ty + kk * 16;
    ushort4 o;
    o.x = f2bf(tile[tx * 4 + 0][nr]);
    o.y = f2bf(tile[tx * 4 + 1][nr]);
    o.z = f2bf(tile[tx * 4 + 2][nr]);
    o.w = f2bf(tile[tx * 4 + 3][nr]);
    *reinterpret_cast<ushort4*>(dst + (n0 + nr) * 256 + a0 + tx * 4) = o;
  }
}

// ---------------- Kernel 2: fused QKVG projection GEMM (bf16 MFMA) ----------
// v7: 128-thr blocks, 32 rows each -> 1024 blocks (was 256 at 1 block/CU).
__global__ __launch_bounds__(128) void proj_k(
    const float* __restrict__ x, const unsigned short* __restrict__ Wt,
    const float* __restrict__ query_b,
    unsigned short* __restrict__ Qg, unsigned short* __restrict__ Kg,
    unsigned short* __restrict__ Vt, float* __restrict__ gate) {
  const int w = threadIdx.x >> 6;
  const int lane = threadIdx.x & 63;
  const int l15 = lane & 15;
  const int quad = lane >> 4;
  const int p = blockIdx.y >> 1;
  const int half = blockIdx.y & 1;
  const int rbase = blockIdx.x * 32 + w * 16;
  const unsigned short* wp = Wt + p * 65536;

  f32x4 acc[8];
#pragma unroll
  for (int ct = 0; ct < 8; ct++) acc[ct] = (f32x4){0.f, 0.f, 0.f, 0.f};

  for (int ks = 0; ks < 8; ks++) {
    const int kb = ks * 32;
    const float* xr = x + (rbase + l15) * 256 + kb + quad * 8;
    float4 f0 = *reinterpret_cast<const float4*>(xr);
    float4 f1 = *reinterpret_cast<const float4*>(xr + 4);
    u16x8 t;
    t[0] = f2bf(f0.x); t[1] = f2bf(f0.y); t[2] = f2bf(f0.z); t[3] = f2bf(f0.w);
    t[4] = f2bf(f1.x); t[5] = f2bf(f1.y); t[6] = f2bf(f1.z); t[7] = f2bf(f1.w);
    s16x8 af = __builtin_bit_cast(s16x8, t);
#pragma unroll
    for (int ct = 0; ct < 8; ct++) {
      uint4 bv = *reinterpret_cast<const uint4*>(
          wp + (half * 128 + ct * 16 + l15) * 256 + kb + quad * 8);
      acc[ct] = __builtin_amdgcn_mfma_f32_16x16x32_bf16(
          af, __builtin_bit_cast(s16x8, bv), acc[ct], 0, 0, 0);
    }
  }

#pragma unroll
  for (int ct = 0; ct < 8; ct++) {
    const int cgl = half * 128 + ct * 16 + l15;
    const int h = cgl >> 5, c = cgl & 31;
    const int n0r = rbase + quad * 4;
    const int bidx = n0r >> 11;
    const int nl0 = n0r & 2047;
    if (p == 0) {
      const float qb = query_b[cgl];
#pragma unroll
      for (int i = 0; i < 4; i++) {
        float v = (acc[ct][i] + qb) * SCALE;
        Qg[(size_t)((bidx * 8 + h) * 2048 + nl0 + i) * 32 + c] = f2bf(v);
      }
    } else if (p == 1) {
#pragma unroll
      for (int i = 0; i < 4; i++)
        Kg[(size_t)((bidx * 8 + h) * 2048 + nl0 + i) * 32 + c] = f2bf(acc[ct][i]);
    } else if (p == 2) {
      ushort4 o;
      o.x = f2bf(acc[ct][0]); o.y = f2bf(acc[ct][1]);
      o.z = f2bf(acc[ct][2]); o.w = f2bf(acc[ct][3]);
      *reinterpret_cast<ushort4*>(Vt + (size_t)((bidx * 8 + h) * 32 + c) * 2048 + nl0) = o;
    } else {
#pragma unroll
      for (int i = 0; i < 4; i++) {
        float s = 1.f / (1.f + __expf(-acc[ct][i]));
        gate[(size_t)(bidx * 2048 + nl0 + i) * 256 + cgl] = s;
      }
    }
  }
}

// ---------------- Kernel 3: flash attention, LDS-staged nb ------------------
// v7: nb prefetch via global_load_lds (zero VGPR footprint -> can't be sunk
// or spilled; R2-R6 showed the register double-buffer is unimplementable).
// Wave = 16q x 1h x 1b x 512-key segment, 64-key tiles. Per tile: K/V/bias
// (L2) issued FIRST, 4x HBM load_lds for t+1 LAST (vmcnt FIFO: compiler K/V
// waits then leave the prefetch in flight), manual vmcnt(4) before consuming
// tile t's nb. Twin b=0/1 blocks dispatch-adjacent -> nb 2nd read hits L3.
// VGPR ~100 (4 waves/SIMD bucket); LDS 21KB/block -> 7 blocks/CU -> 14 w/CU.
#define PST 72  // Ps row stride (shorts)
__global__ __launch_bounds__(128, 4) void attn_k(
    const unsigned short* __restrict__ Qg, const unsigned short* __restrict__ Kg,
    const unsigned short* __restrict__ Vt, const float* __restrict__ bias,
    const float* __restrict__ nb, float* __restrict__ out,
    float* __restrict__ psum_g) {
  __shared__ __align__(16) float NbS[2][2][16 * 64];  // [wave][buf][16q x 64k]
  __shared__ __align__(16) unsigned short Ps[2][16 * PST];
  const int w = threadIdx.x >> 6;
  const int lane = threadIdx.x & 63;
  const int l15 = lane & 15;
  const int quad = lane >> 4;
  const int h = blockIdx.y;
  const int b = blockIdx.z & 1;        // b fastest: twins adjacent for L3 reuse
  const int seg = blockIdx.z >> 1;     // 4-way key split: 512 keys
  const int qbase = blockIdx.x * 32 + w * 16;
  const int qr0 = qbase + quad * 4;    // C-layout row of i=0
  const int bh = b * 8 + h;
  const unsigned short* Kp = Kg + (size_t)bh * 2048 * 32;
  const unsigned short* Vp = Vt + (size_t)bh * 32 * 2048;
  const float* nbp = nb + (size_t)h * 2048 * 2048;
  unsigned short* Pw = &Ps[w][0];
  const int kb0 = seg * 512;

  // Q A-frag: A[m=l15][k=quad*8+j], fixed for whole loop.
  s16x8 aq = __builtin_bit_cast(s16x8, *reinterpret_cast<const uint4*>(
      Qg + (size_t)(bh * 2048 + qbase + l15) * 32 + quad * 8));

  float psum[4];
  f32x4 o[2];
#pragma unroll
  for (int i = 0; i < 4; i++) psum[i] = 0.f;
#pragma unroll
  for (int vt = 0; vt < 2; vt++) o[vt] = (f32x4){0.f, 0.f, 0.f, 0.f};

  // Stage first nb tile (16q x 64k f32 = 4 chunks of 1KB).
#pragma unroll
  for (int j = 0; j < 4; j++)
    gld_lds16(nbp + (size_t)(qbase + j * 4 + quad) * 2048 + kb0 + l15 * 4,
              &NbS[w][0][j * 256]);

#pragma unroll 2
  for (int t = 0; t < 8; t++) {
    const int kb = kb0 + t * 64;
    const int cur = t & 1, nxt = cur ^ 1;

    // K/V/bias for this tile (L2-hot), issued BEFORE the HBM prefetch.
    s16x8 bk[4];
#pragma unroll
    for (int ct = 0; ct < 4; ct++)
      bk[ct] = __builtin_bit_cast(s16x8, *reinterpret_cast<const uint4*>(
          Kp + (size_t)(kb + ct * 16 + l15) * 32 + quad * 8));
    s16x8 vv[4];
#pragma unroll
    for (int kc = 0; kc < 2; kc++)
#pragma unroll
      for (int vt = 0; vt < 2; vt++)
        vv[kc * 2 + vt] = __builtin_bit_cast(s16x8, *reinterpret_cast<const uint4*>(
            Vp + (size_t)(vt * 16 + l15) * 2048 + kb + kc * 32 + quad * 8));
    float bbv[4];
#pragma unroll
    for (int ct = 0; ct < 4; ct++)
      bbv[ct] = bias[b * 2048 + kb + ct * 16 + l15] - 20.f;  // static-max fold

    // HBM prefetch of next nb tile - LAST issued, so K/V waits keep it flying.
    if (t < 7) {
#pragma unroll
      for (int j = 0; j < 4; j++)
        gld_lds16(nbp + (size_t)(qbase + j * 4 + quad) * 2048 + kb + 64 + l15 * 4,
                  &NbS[w][nxt][j * 256]);
    }

    // S = Q K^T (one MFMA per 16x16 tile: K=32 = full head dim).
    f32x4 s[4];
#pragma unroll
    for (int ct = 0; ct < 4; ct++)
      s[ct] = __builtin_amdgcn_mfma_f32_16x16x32_bf16(
          aq, bk[ct], (f32x4){0.f, 0.f, 0.f, 0.f}, 0, 0, 0);

    // Consume tile t's nb from LDS. vmcnt(4): drain everything except the 4
    // newest (the prefetch). imm = vmcnt4 | expcnt7<<4 | lgkmcnt15<<8.
    __builtin_amdgcn_s_waitcnt(0x0F74);
    float nbv[16];
    const float* nbc = &NbS[w][cur][0];
#pragma unroll
    for (int ct = 0; ct < 4; ct++)
#pragma unroll
      for (int i = 0; i < 4; i++)
        nbv[ct * 4 + i] = nbc[(quad * 4 + i) * 64 + ct * 16 + l15];

    // Static-max softmax: p = exp(s + bias + nb - 20); sum deferred.
#pragma unroll
    for (int ct = 0; ct < 4; ct++)
#pragma unroll
      for (int i = 0; i < 4; i++) {
        float pv = __expf(s[ct][i] + bbv[ct] + nbv[ct * 4 + i]);
        Pw[(quad * 4 + i) * PST + ct * 16 + l15] = f2bf(pv);
        psum[i] += pv;
      }

    // PV: A = P from LDS (wave-private slice), B = V^T frags.
#pragma unroll
    for (int kc = 0; kc < 2; kc++) {
      s16x8 ap = __builtin_bit_cast(s16x8, *reinterpret_cast<const uint4*>(
          &Pw[l15 * PST + kc * 32 + quad * 8]));
#pragma unroll
      for (int vt = 0; vt < 2; vt++)
        o[vt] = __builtin_amdgcn_mfma_f32_16x16x32_bf16(ap, vv[kc * 2 + vt],
                                                        o[vt], 0, 0, 0);
    }
  }

  // Epilogue: atomically accumulate split-K partials (unnormalized).
#pragma unroll
  for (int i = 0; i < 4; i++) {
    float l = psum[i];
    l += __shfl_xor(l, 1);
    l += __shfl_xor(l, 2);
    l += __shfl_xor(l, 4);
    l += __shfl_xor(l, 8);
    const int q = qr0 + i;
    if (l15 == 0) atomicAdd(&psum_g[(size_t)bh * 2048 + q], l);
#pragma unroll
    for (int vt = 0; vt < 2; vt++) {
      const int v = vt * 16 + l15;
      atomicAdd(&out[(size_t)(b * 2048 + q) * 256 + h * 32 + v], o[vt][i]);
    }
  }
}

// ---------------- Kernel 4: normalize + gate --------------------------------
__global__ __launch_bounds__(256) void finish_k(
    float* __restrict__ out, const float* __restrict__ gate,
    const float* __restrict__ psum_g) {
  const int i4 = blockIdx.x * 256 + threadIdx.x;   // float4 index, 262144 total
  const int flat = i4 * 4;
  const int b = flat >> 19;
  const int rem = flat & 524287;
  const int q = rem >> 8;
  const int c = rem & 255;
  const int h = c >> 5;
  const float inv = 1.f / psum_g[(size_t)(b * 8 + h) * 2048 + q];
  float4 o = reinterpret_cast<float4*>(out)[i4];
  float4 g = reinterpret_cast<const float4*>(gate)[i4];
  o.x *= inv * g.x; o.y *= inv * g.y; o.z *= inv * g.z; o.w *= inv * g.w;
  reinterpret_cast<float4*>(out)[i4] = o;
}

// ---------------- launch ----------------------------------------------------
extern "C" void kernel_launch(void* const* d_in, const int* in_sizes, int n_in,
                              void* d_out, int out_size, void* d_ws, size_t ws_size,
                              hipStream_t stream) {
  const float* q_data = (const float*)d_in[0];
  const float* bias = (const float*)d_in[1];
  const float* nbb = (const float*)d_in[2];
  const float* qw = (const float*)d_in[3];
  const float* qb = (const float*)d_in[4];
  const float* kw = (const float*)d_in[5];
  const float* vw = (const float*)d_in[6];
  const float* gw = (const float*)d_in[7];
  float* out = (float*)d_out;

  char* ws = (char*)d_ws;
  // ws layout (10.63 MB): Wt 512K | Qg 2M | Kg 2M | Vt 2M | gate 4M | psum 128K
  unsigned short* Wt = (unsigned short*)(ws + 0);
  unsigned short* Qg = (unsigned short*)(ws + 524288);
  unsigned short* Kg = (unsigned short*)(ws + 2621440);
  unsigned short* Vt = (unsigned short*)(ws + 4718592);
  float* gate = (float*)(ws + 6815744);
  float* psum_g = (float*)(ws + 11010048);

  hipMemsetAsync(out, 0, (size_t)out_size * sizeof(float), stream);
  hipMemsetAsync(psum_g, 0, 2 * 8 * 2048 * sizeof(float), stream);
  prep_weights_k<<<dim3(4, 4, 4), 256, 0, stream>>>(qw, kw, vw, gw, Wt);
  proj_k<<<dim3(128, 8), 128, 0, stream>>>(q_data, Wt, qb, Qg, Kg, Vt, gate);
  attn_k<<<dim3(64, 8, 8), 128, 0, stream>>>(Qg, Kg, Vt, bias, nbb, out, psum_g);
  finish_k<<<dim3(1024), 256, 0, stream>>>(out, gate, psum_g);
}